// Round 1
// baseline (184.251 us; speedup 1.0000x reference)
//
#include <hip/hip_runtime.h>
#include <math.h>

#define B_ 1024
#define I_ 256
#define N_ 1024
#define O_ 256
#define EPSV 1e-5f

// ---------------------------------------------------------------------------
// Pre-pass: row norms of x (per b) and column norms of G (per n), re & im.
// blocks [0, B_): xsq for row b (64 lanes, float4 loads, wave reduce)
// blocks [B_, B_+16): gsq for 64 columns each (coalesced column sweep)
// ---------------------------------------------------------------------------
__global__ __launch_bounds__(64) void pre_kernel(
    const float* __restrict__ x_re, const float* __restrict__ x_im,
    const float* __restrict__ G_re, const float* __restrict__ G_im,
    float* __restrict__ xsq_re, float* __restrict__ xsq_im,
    float* __restrict__ gsq_re, float* __restrict__ gsq_im)
{
    const int bid  = blockIdx.x;
    const int lane = threadIdx.x;   // 0..63
    if (bid < B_) {
        const float4* xr = (const float4*)(x_re + (size_t)bid * I_);
        const float4* xi = (const float4*)(x_im + (size_t)bid * I_);
        float4 a = xr[lane];        // I_/4 = 64 float4 per row
        float4 c = xi[lane];
        float sr = a.x*a.x + a.y*a.y + a.z*a.z + a.w*a.w;
        float si = c.x*c.x + c.y*c.y + c.z*c.z + c.w*c.w;
        #pragma unroll
        for (int off = 32; off > 0; off >>= 1) {
            sr += __shfl_down(sr, off);
            si += __shfl_down(si, off);
        }
        if (lane == 0) { xsq_re[bid] = sr; xsq_im[bid] = si; }
    } else {
        const int n = (bid - B_) * 64 + lane;
        float sr = 0.f, si = 0.f;
        for (int i = 0; i < I_; ++i) {
            float g = G_re[(size_t)i * N_ + n]; sr += g * g;
            float h = G_im[(size_t)i * N_ + n]; si += h * h;
        }
        gsq_re[n] = sr; gsq_im[n] = si;
    }
}

// ---------------------------------------------------------------------------
// phi GEMM: C = X @ G (re and im in parallel), epilogue
//   v = xsq[b] - 2*C + gsq[n];  phi = exp(-v / max(s, eps))
// 64x64 tile, 256 threads, 4x4 micro-tile, K-tile 16. Grid 16x16 = 256 blocks.
// ---------------------------------------------------------------------------
__global__ __launch_bounds__(256) void phi_kernel(
    const float* __restrict__ Xr, const float* __restrict__ Xi,
    const float* __restrict__ Gr, const float* __restrict__ Gi,
    const float* __restrict__ xsq_re, const float* __restrict__ xsq_im,
    const float* __restrict__ gsq_re, const float* __restrict__ gsq_im,
    const float* __restrict__ s_re, const float* __restrict__ s_im,
    float* __restrict__ Pr, float* __restrict__ Pi)
{
    // stride 68 floats = 272 B, 16B-aligned rows so float4 LDS ops stay aligned
    __shared__ float Ar[16][68], Ai[16][68], Br[16][68], Bi[16][68];
    const int tid = threadIdx.x;
    const int tx = tid & 15, ty = tid >> 4;
    const int m0 = blockIdx.y * 64, n0 = blockIdx.x * 64;

    float cr[4][4] = {}, ci[4][4] = {};

    const int lm = tid >> 2, lq = tid & 3;    // A-tile loader: row lm, quad lq
    const int lk = tid >> 4, ls = tid & 15;   // B-tile loader: k-row lk, seg ls

    for (int k0 = 0; k0 < I_; k0 += 16) {
        float4 a_r = *(const float4*)(Xr + (size_t)(m0 + lm) * I_ + k0 + lq * 4);
        float4 a_i = *(const float4*)(Xi + (size_t)(m0 + lm) * I_ + k0 + lq * 4);
        float4 b_r = *(const float4*)(Gr + (size_t)(k0 + lk) * N_ + n0 + ls * 4);
        float4 b_i = *(const float4*)(Gi + (size_t)(k0 + lk) * N_ + n0 + ls * 4);
        // A stored transposed: Ar[k][m]
        Ar[lq*4+0][lm] = a_r.x; Ar[lq*4+1][lm] = a_r.y;
        Ar[lq*4+2][lm] = a_r.z; Ar[lq*4+3][lm] = a_r.w;
        Ai[lq*4+0][lm] = a_i.x; Ai[lq*4+1][lm] = a_i.y;
        Ai[lq*4+2][lm] = a_i.z; Ai[lq*4+3][lm] = a_i.w;
        *(float4*)&Br[lk][ls*4] = b_r;
        *(float4*)&Bi[lk][ls*4] = b_i;
        __syncthreads();

        #pragma unroll
        for (int kk = 0; kk < 16; ++kk) {
            float4 ar4 = *(const float4*)&Ar[kk][ty*4];
            float4 ai4 = *(const float4*)&Ai[kk][ty*4];
            float4 br4 = *(const float4*)&Br[kk][tx*4];
            float4 bi4 = *(const float4*)&Bi[kk][tx*4];
            float arr[4] = {ar4.x, ar4.y, ar4.z, ar4.w};
            float aii[4] = {ai4.x, ai4.y, ai4.z, ai4.w};
            float brr[4] = {br4.x, br4.y, br4.z, br4.w};
            float bii[4] = {bi4.x, bi4.y, bi4.z, bi4.w};
            #pragma unroll
            for (int i = 0; i < 4; ++i)
                #pragma unroll
                for (int j = 0; j < 4; ++j) {
                    cr[i][j] = fmaf(arr[i], brr[j], cr[i][j]);
                    ci[i][j] = fmaf(aii[i], bii[j], ci[i][j]);
                }
        }
        __syncthreads();
    }

    #pragma unroll
    for (int i = 0; i < 4; ++i) {
        const int m = m0 + ty * 4 + i;
        const float xr  = xsq_re[m];
        const float xi2 = xsq_im[m];
        #pragma unroll
        for (int j = 0; j < 4; ++j) {
            const int n = n0 + tx * 4 + j;
            const float vr = xr  - 2.f * cr[i][j] + gsq_re[n];
            const float vi = xi2 - 2.f * ci[i][j] + gsq_im[n];
            const float pr = expf(-vr / fmaxf(s_re[n], EPSV));
            const float pi = expf(-vi / fmaxf(s_im[n], EPSV));
            Pr[(size_t)m * N_ + n] = pr;
            Pi[(size_t)m * N_ + n] = pi;
        }
    }
}

// ---------------------------------------------------------------------------
// Complex GEMM: y_re = Pr@Wr - Pi@Wi + b_re;  y_im = Pr@Wi + Pi@Wr + b_im
// 32x32 tile, 256 threads, 2x2 micro-tile, K-tile 32. Grid 8x32 = 256 blocks.
// Output interleaved: out[(b*O + o)*2 + {0:re, 1:im}]
// ---------------------------------------------------------------------------
__global__ __launch_bounds__(256) void y_kernel(
    const float* __restrict__ Pr, const float* __restrict__ Pi,
    const float* __restrict__ Wr, const float* __restrict__ Wi,
    const float* __restrict__ b_re, const float* __restrict__ b_im,
    float* __restrict__ out)
{
    // stride 36 floats = 144 B (16B-aligned rows)
    __shared__ float Apr[32][36], Api[32][36], Bwr[32][36], Bwi[32][36];
    const int tid = threadIdx.x;
    const int tx = tid & 15, ty = tid >> 4;
    const int m0 = blockIdx.y * 32, n0 = blockIdx.x * 32;

    float yr[2][2] = {}, yi[2][2] = {};

    const int lm = tid >> 3, lq = tid & 7;  // 32 rows x 8 quads (=32 floats)

    for (int k0 = 0; k0 < N_; k0 += 32) {
        float4 p_r = *(const float4*)(Pr + (size_t)(m0 + lm) * N_ + k0 + lq * 4);
        float4 p_i = *(const float4*)(Pi + (size_t)(m0 + lm) * N_ + k0 + lq * 4);
        float4 w_r = *(const float4*)(Wr + (size_t)(k0 + lm) * O_ + n0 + lq * 4);
        float4 w_i = *(const float4*)(Wi + (size_t)(k0 + lm) * O_ + n0 + lq * 4);
        Apr[lq*4+0][lm] = p_r.x; Apr[lq*4+1][lm] = p_r.y;
        Apr[lq*4+2][lm] = p_r.z; Apr[lq*4+3][lm] = p_r.w;
        Api[lq*4+0][lm] = p_i.x; Api[lq*4+1][lm] = p_i.y;
        Api[lq*4+2][lm] = p_i.z; Api[lq*4+3][lm] = p_i.w;
        *(float4*)&Bwr[lm][lq*4] = w_r;
        *(float4*)&Bwi[lm][lq*4] = w_i;
        __syncthreads();

        #pragma unroll
        for (int kk = 0; kk < 32; ++kk) {
            float2 pr2 = *(const float2*)&Apr[kk][ty*2];
            float2 pi2 = *(const float2*)&Api[kk][ty*2];
            float2 wr2 = *(const float2*)&Bwr[kk][tx*2];
            float2 wi2 = *(const float2*)&Bwi[kk][tx*2];
            float prr[2] = {pr2.x, pr2.y}, pii[2] = {pi2.x, pi2.y};
            float wrr[2] = {wr2.x, wr2.y}, wii[2] = {wi2.x, wi2.y};
            #pragma unroll
            for (int i = 0; i < 2; ++i)
                #pragma unroll
                for (int j = 0; j < 2; ++j) {
                    yr[i][j] = fmaf(prr[i],  wrr[j], yr[i][j]);
                    yr[i][j] = fmaf(-pii[i], wii[j], yr[i][j]);
                    yi[i][j] = fmaf(prr[i],  wii[j], yi[i][j]);
                    yi[i][j] = fmaf(pii[i],  wrr[j], yi[i][j]);
                }
        }
        __syncthreads();
    }

    #pragma unroll
    for (int i = 0; i < 2; ++i) {
        const int m = m0 + ty * 2 + i;
        const int n = n0 + tx * 2;
        float4 o;
        o.x = yr[i][0] + b_re[n];
        o.y = yi[i][0] + b_im[n];
        o.z = yr[i][1] + b_re[n + 1];
        o.w = yi[i][1] + b_im[n + 1];
        *(float4*)(out + ((size_t)m * O_ + n) * 2) = o;
    }
}

extern "C" void kernel_launch(void* const* d_in, const int* in_sizes, int n_in,
                              void* d_out, int out_size, void* d_ws, size_t ws_size,
                              hipStream_t stream) {
    const float* x_re = (const float*)d_in[0];
    const float* x_im = (const float*)d_in[1];
    const float* G_re = (const float*)d_in[2];
    const float* G_im = (const float*)d_in[3];
    const float* s_re = (const float*)d_in[4];
    const float* s_im = (const float*)d_in[5];
    const float* W_re = (const float*)d_in[6];
    const float* W_im = (const float*)d_in[7];
    const float* b_re = (const float*)d_in[8];
    const float* b_im = (const float*)d_in[9];
    float* out = (float*)d_out;

    float* ws = (float*)d_ws;
    float* Pr     = ws;                          // 1M floats
    float* Pi     = Pr + (size_t)B_ * N_;        // 1M floats
    float* xsq_re = Pi + (size_t)B_ * N_;
    float* xsq_im = xsq_re + B_;
    float* gsq_re = xsq_im + B_;
    float* gsq_im = gsq_re + N_;

    pre_kernel<<<B_ + N_ / 64, 64, 0, stream>>>(
        x_re, x_im, G_re, G_im, xsq_re, xsq_im, gsq_re, gsq_im);

    phi_kernel<<<dim3(N_ / 64, B_ / 64), 256, 0, stream>>>(
        x_re, x_im, G_re, G_im, xsq_re, xsq_im, gsq_re, gsq_im,
        s_re, s_im, Pr, Pi);

    y_kernel<<<dim3(O_ / 32, B_ / 32), 256, 0, stream>>>(
        Pr, Pi, W_re, W_im, b_re, b_im, out);
}

// Round 2
// 164.896 us; speedup vs baseline: 1.1174x; 1.1174x over previous
//
#include <hip/hip_runtime.h>
#include <math.h>

#define B_ 1024
#define I_ 256
#define N_ 1024
#define O_ 256
#define EPSV 1e-5f

// ---------------------------------------------------------------------------
// Pre-pass: row norms of x (per b) and column norms of G (per n), re & im.
// ---------------------------------------------------------------------------
__global__ __launch_bounds__(64) void pre_kernel(
    const float* __restrict__ x_re, const float* __restrict__ x_im,
    const float* __restrict__ G_re, const float* __restrict__ G_im,
    float* __restrict__ xsq_re, float* __restrict__ xsq_im,
    float* __restrict__ gsq_re, float* __restrict__ gsq_im)
{
    const int bid  = blockIdx.x;
    const int lane = threadIdx.x;   // 0..63
    if (bid < B_) {
        const float4* xr = (const float4*)(x_re + (size_t)bid * I_);
        const float4* xi = (const float4*)(x_im + (size_t)bid * I_);
        float4 a = xr[lane];
        float4 c = xi[lane];
        float sr = a.x*a.x + a.y*a.y + a.z*a.z + a.w*a.w;
        float si = c.x*c.x + c.y*c.y + c.z*c.z + c.w*c.w;
        #pragma unroll
        for (int off = 32; off > 0; off >>= 1) {
            sr += __shfl_down(sr, off);
            si += __shfl_down(si, off);
        }
        if (lane == 0) { xsq_re[bid] = sr; xsq_im[bid] = si; }
    } else {
        const int n = (bid - B_) * 64 + lane;
        float sr = 0.f, si = 0.f;
        for (int i = 0; i < I_; ++i) {
            float g = G_re[(size_t)i * N_ + n]; sr += g * g;
            float h = G_im[(size_t)i * N_ + n]; si += h * h;
        }
        gsq_re[n] = sr; gsq_im[n] = si;
    }
}

// ---------------------------------------------------------------------------
// Bias init: d_out is poisoned 0xAA before every launch; write bias so the
// split-K y_kernel can atomicAdd partials on top.
// out[(m*O + o)*2 + {0,1}] = {b_re[o], b_im[o]}; one float4 covers o, o+1.
// ---------------------------------------------------------------------------
__global__ __launch_bounds__(256) void init_kernel(
    const float* __restrict__ b_re, const float* __restrict__ b_im,
    float* __restrict__ out)
{
    const int idx = blockIdx.x * 256 + threadIdx.x;  // 0 .. 131071
    const int q = idx & 127;                         // float4 within row
    const int o = q * 2;
    float4 v;
    v.x = b_re[o];     v.y = b_im[o];
    v.z = b_re[o + 1]; v.w = b_im[o + 1];
    *((float4*)out + idx) = v;
}

// ---------------------------------------------------------------------------
// phi GEMM: C = X @ G (re & im), epilogue v = xsq - 2C + gsq, phi = exp(-v/s)
// Tile 32(B) x 64(N), K-tile 32, 256 threads, 2x4 micro-tile.
// Grid 16 x 32 = 512 blocks -> 2 blocks/CU -> 8 waves/CU.
// ---------------------------------------------------------------------------
__global__ __launch_bounds__(256) void phi_kernel(
    const float* __restrict__ Xr, const float* __restrict__ Xi,
    const float* __restrict__ Gr, const float* __restrict__ Gi,
    const float* __restrict__ xsq_re, const float* __restrict__ xsq_im,
    const float* __restrict__ gsq_re, const float* __restrict__ gsq_im,
    const float* __restrict__ s_re, const float* __restrict__ s_im,
    float* __restrict__ Pr, float* __restrict__ Pi)
{
    __shared__ float Ar[32][34], Ai[32][34];   // A transposed: [k][m], m=32
    __shared__ float Br[32][68], Bi[32][68];   // B: [k][n], n=64
    const int tid = threadIdx.x;
    const int tx = tid & 15, ty = tid >> 4;    // micro: 2 rows (ty), 4 cols (tx)
    const int m0 = blockIdx.y * 32, n0 = blockIdx.x * 64;

    float cr[2][4] = {}, ci[2][4] = {};

    const int lm = tid >> 3, lq = tid & 7;     // A loader: row lm(0..31), quad lq
    const int lk = tid >> 4, ls = tid & 15;    // B loader: k-row lk(0..15), seg ls

    for (int k0 = 0; k0 < I_; k0 += 32) {
        float4 a_r = *(const float4*)(Xr + (size_t)(m0 + lm) * I_ + k0 + lq * 4);
        float4 a_i = *(const float4*)(Xi + (size_t)(m0 + lm) * I_ + k0 + lq * 4);
        float4 b_r0 = *(const float4*)(Gr + (size_t)(k0 + lk) * N_ + n0 + ls * 4);
        float4 b_i0 = *(const float4*)(Gi + (size_t)(k0 + lk) * N_ + n0 + ls * 4);
        float4 b_r1 = *(const float4*)(Gr + (size_t)(k0 + lk + 16) * N_ + n0 + ls * 4);
        float4 b_i1 = *(const float4*)(Gi + (size_t)(k0 + lk + 16) * N_ + n0 + ls * 4);
        Ar[lq*4+0][lm] = a_r.x; Ar[lq*4+1][lm] = a_r.y;
        Ar[lq*4+2][lm] = a_r.z; Ar[lq*4+3][lm] = a_r.w;
        Ai[lq*4+0][lm] = a_i.x; Ai[lq*4+1][lm] = a_i.y;
        Ai[lq*4+2][lm] = a_i.z; Ai[lq*4+3][lm] = a_i.w;
        *(float4*)&Br[lk][ls*4]      = b_r0;
        *(float4*)&Bi[lk][ls*4]      = b_i0;
        *(float4*)&Br[lk + 16][ls*4] = b_r1;
        *(float4*)&Bi[lk + 16][ls*4] = b_i1;
        __syncthreads();

        #pragma unroll
        for (int kk = 0; kk < 32; ++kk) {
            float2 ar2 = *(const float2*)&Ar[kk][ty*2];
            float2 ai2 = *(const float2*)&Ai[kk][ty*2];
            float4 br4 = *(const float4*)&Br[kk][tx*4];
            float4 bi4 = *(const float4*)&Bi[kk][tx*4];
            float arr[2] = {ar2.x, ar2.y};
            float aii[2] = {ai2.x, ai2.y};
            float brr[4] = {br4.x, br4.y, br4.z, br4.w};
            float bii[4] = {bi4.x, bi4.y, bi4.z, bi4.w};
            #pragma unroll
            for (int i = 0; i < 2; ++i)
                #pragma unroll
                for (int j = 0; j < 4; ++j) {
                    cr[i][j] = fmaf(arr[i], brr[j], cr[i][j]);
                    ci[i][j] = fmaf(aii[i], bii[j], ci[i][j]);
                }
        }
        __syncthreads();
    }

    #pragma unroll
    for (int i = 0; i < 2; ++i) {
        const int m = m0 + ty * 2 + i;
        const float xr  = xsq_re[m];
        const float xi2 = xsq_im[m];
        float4 pr4, pi4;
        float* prp = &pr4.x;
        float* pip = &pi4.x;
        #pragma unroll
        for (int j = 0; j < 4; ++j) {
            const int n = n0 + tx * 4 + j;
            const float vr = xr  - 2.f * cr[i][j] + gsq_re[n];
            const float vi = xi2 - 2.f * ci[i][j] + gsq_im[n];
            prp[j] = expf(-vr / fmaxf(s_re[n], EPSV));
            pip[j] = expf(-vi / fmaxf(s_im[n], EPSV));
        }
        *(float4*)(Pr + (size_t)m * N_ + n0 + tx * 4) = pr4;
        *(float4*)(Pi + (size_t)m * N_ + n0 + tx * 4) = pi4;
    }
}

// ---------------------------------------------------------------------------
// Complex GEMM, split-K: y_re += Pr@Wr - Pi@Wi ; y_im += Pr@Wi + Pi@Wr
// Tile 32x32, K split into 4 chunks of 256, K-tile 32, 256 threads, 2x2 micro.
// Grid 8 x 32 x 4 = 1024 blocks -> 4 blocks/CU -> 16 waves/CU.
// Partials atomicAdd onto out (pre-initialized with bias by init_kernel).
// ---------------------------------------------------------------------------
__global__ __launch_bounds__(256) void y_kernel(
    const float* __restrict__ Pr, const float* __restrict__ Pi,
    const float* __restrict__ Wr, const float* __restrict__ Wi,
    float* __restrict__ out)
{
    __shared__ float Apr[32][34], Api[32][34];  // A transposed: [k][m]
    __shared__ float Bwr[32][36], Bwi[32][36];  // B: [k][n]
    const int tid = threadIdx.x;
    const int tx = tid & 15, ty = tid >> 4;     // micro 2x2
    const int m0 = blockIdx.y * 32, n0 = blockIdx.x * 32;
    const int k_base = blockIdx.z * 256;

    float yr[2][2] = {}, yi[2][2] = {};

    const int lm = tid >> 3, lq = tid & 7;      // loaders: row lm(0..31), quad lq

    for (int k0 = k_base; k0 < k_base + 256; k0 += 32) {
        float4 p_r = *(const float4*)(Pr + (size_t)(m0 + lm) * N_ + k0 + lq * 4);
        float4 p_i = *(const float4*)(Pi + (size_t)(m0 + lm) * N_ + k0 + lq * 4);
        float4 w_r = *(const float4*)(Wr + (size_t)(k0 + lm) * O_ + n0 + lq * 4);
        float4 w_i = *(const float4*)(Wi + (size_t)(k0 + lm) * O_ + n0 + lq * 4);
        Apr[lq*4+0][lm] = p_r.x; Apr[lq*4+1][lm] = p_r.y;
        Apr[lq*4+2][lm] = p_r.z; Apr[lq*4+3][lm] = p_r.w;
        Api[lq*4+0][lm] = p_i.x; Api[lq*4+1][lm] = p_i.y;
        Api[lq*4+2][lm] = p_i.z; Api[lq*4+3][lm] = p_i.w;
        *(float4*)&Bwr[lm][lq*4] = w_r;
        *(float4*)&Bwi[lm][lq*4] = w_i;
        __syncthreads();

        #pragma unroll
        for (int kk = 0; kk < 32; ++kk) {
            float2 pr2 = *(const float2*)&Apr[kk][ty*2];
            float2 pi2 = *(const float2*)&Api[kk][ty*2];
            float2 wr2 = *(const float2*)&Bwr[kk][tx*2];
            float2 wi2 = *(const float2*)&Bwi[kk][tx*2];
            float prr[2] = {pr2.x, pr2.y}, pii[2] = {pi2.x, pi2.y};
            float wrr[2] = {wr2.x, wr2.y}, wii[2] = {wi2.x, wi2.y};
            #pragma unroll
            for (int i = 0; i < 2; ++i)
                #pragma unroll
                for (int j = 0; j < 2; ++j) {
                    yr[i][j] = fmaf(prr[i],  wrr[j], yr[i][j]);
                    yr[i][j] = fmaf(-pii[i], wii[j], yr[i][j]);
                    yi[i][j] = fmaf(prr[i],  wii[j], yi[i][j]);
                    yi[i][j] = fmaf(pii[i],  wrr[j], yi[i][j]);
                }
        }
        __syncthreads();
    }

    #pragma unroll
    for (int i = 0; i < 2; ++i) {
        const int m = m0 + ty * 2 + i;
        #pragma unroll
        for (int j = 0; j < 2; ++j) {
            const int n = n0 + tx * 2 + j;
            atomicAdd(out + ((size_t)m * O_ + n) * 2,     yr[i][j]);
            atomicAdd(out + ((size_t)m * O_ + n) * 2 + 1, yi[i][j]);
        }
    }
}

extern "C" void kernel_launch(void* const* d_in, const int* in_sizes, int n_in,
                              void* d_out, int out_size, void* d_ws, size_t ws_size,
                              hipStream_t stream) {
    const float* x_re = (const float*)d_in[0];
    const float* x_im = (const float*)d_in[1];
    const float* G_re = (const float*)d_in[2];
    const float* G_im = (const float*)d_in[3];
    const float* s_re = (const float*)d_in[4];
    const float* s_im = (const float*)d_in[5];
    const float* W_re = (const float*)d_in[6];
    const float* W_im = (const float*)d_in[7];
    const float* b_re = (const float*)d_in[8];
    const float* b_im = (const float*)d_in[9];
    float* out = (float*)d_out;

    float* ws = (float*)d_ws;
    float* Pr     = ws;
    float* Pi     = Pr + (size_t)B_ * N_;
    float* xsq_re = Pi + (size_t)B_ * N_;
    float* xsq_im = xsq_re + B_;
    float* gsq_re = xsq_im + B_;
    float* gsq_im = gsq_re + N_;

    pre_kernel<<<B_ + N_ / 64, 64, 0, stream>>>(
        x_re, x_im, G_re, G_im, xsq_re, xsq_im, gsq_re, gsq_im);

    init_kernel<<<(B_ * O_ * 2 / 4) / 256, 256, 0, stream>>>(b_re, b_im, out);

    phi_kernel<<<dim3(N_ / 64, B_ / 32), 256, 0, stream>>>(
        x_re, x_im, G_re, G_im, xsq_re, xsq_im, gsq_re, gsq_im,
        s_re, s_im, Pr, Pi);

    y_kernel<<<dim3(O_ / 32, B_ / 32, 4), 256, 0, stream>>>(
        Pr, Pi, W_re, W_im, out);
}